// Round 13
// baseline (775.350 us; speedup 1.0000x reference)
//
#include <hip/hip_runtime.h>
#include <hip/hip_fp16.h>
#include <cstddef>

#define N_NODES  50000
#define N_EDGES  600000
#define N_FEAT   128
#define N_GRAPHS 256
#define DIMM     95
#define N_OUTD   12
#define N_ITERS  10

#define SR 132   // padded LDS row stride (128+4); 132*4B = 16B-aligned rows
#define TR 48    // rows per tile; tile == block for k_fused
#define N_TILES  ((N_NODES + TR - 1) / TR)   // 1042
#define CAP 1024 // edge slots per tile (mean 576, max bin ~665 by balls-in-bins)

// workspace layout (float-element offsets; int/half arrays reinterpret)
#define WS_STATS 0                         // [256] colsum[128], colsumsq[128]
#define WS_XG    (WS_STATS + 256)          // [256*128] raw pooled sums
#define WS_CUR   (WS_XG + N_GRAPHS * N_FEAT)   // int[1042] bucket cursors
#define WS_BUCK  (WS_CUR + N_TILES + 2)        // int[1042*1024] (rel<<16)|src
#define WS_XH    (WS_BUCK + N_TILES * CAP)     // half[50000*128] fp16 x table

// ---- prep: zero stats/pools/cursors + cast x->fp16 -------------------------
__global__ void k_pre(const float* __restrict__ x, float* __restrict__ ws) {
    const int gtid = blockIdx.x * 256 + threadIdx.x;
    const int nthr = gridDim.x * 256;
    for (int i = gtid; i < 256 + N_GRAPHS * N_FEAT; i += nthr) ws[i] = 0.f;
    int* cur = (int*)ws + WS_CUR;
    for (int i = gtid; i < N_TILES; i += nthr) cur[i] = 0;
    const float4* __restrict__ x4 = (const float4*)x;
    float2* __restrict__ xh = (float2*)(ws + WS_XH);
    for (int i = gtid; i < N_NODES * 32; i += nthr) {
        float4 v = x4[i];
        float2 o;
        ((__half2*)&o)[0] = __float22half2_rn(make_float2(v.x, v.y));
        ((__half2*)&o)[1] = __float22half2_rn(make_float2(v.z, v.w));
        xh[i] = o;
    }
}

// ---- direct bucket scatter: ONE pass over edges ----------------------------
// Edge -> tile bucket via per-tile atomic cursor. Counts are deterministic.
__global__ void k_bucket(const int* __restrict__ ei, float* __restrict__ ws) {
    int e = blockIdx.x * 256 + threadIdx.x;
    if (e >= N_EDGES) return;
    int d = ei[N_EDGES + e];
    int s = ei[e];
    int t = d / TR;
    int rel = d - t * TR;
    int* cur = (int*)ws + WS_CUR;
    int pos = atomicAdd(&cur[t], 1);
    if (pos < CAP) ((int*)ws + WS_BUCK)[t * CAP + pos] = (rel << 16) | s;
}

// ---- fused: LDS-atomic edge accumulate + 2-layer MLP + stats/pool partials -
// No sort: As tile init'd with fp32 self term; each edge adds its fp16 row
// via ds_add_f32 (order-independent modulo fp32 rounding, like R2's k_agg).
__global__ __launch_bounds__(256, 4) void k_fused(const float* __restrict__ x,
        const int* __restrict__ batch, float* __restrict__ ws,
        const float* __restrict__ W1a, const float* __restrict__ b1a,
        const float* __restrict__ W1b, const float* __restrict__ b1b) {
    __shared__ float As[TR * SR];      // float-only; never aliased as int
    __shared__ float red[256];
    __shared__ int batch_l[TR];
    const int tid  = threadIdx.x;
    const int lane = tid & 63;
    const int wv   = tid >> 6;
    const int fg   = tid & 15;     // 16 feat groups x 8 cols (MLP)
    const int rg   = tid >> 4;     // 16 row groups  x 3 rows (MLP)
    const int tile = blockIdx.x;
    const int row0 = tile * TR;

    const float2* __restrict__ x2 = (const float2*)x;
    const __half2* __restrict__ xh2 = (const __half2*)(ws + WS_XH);  // 64/row

    // ---- init: As row <- fp32 self term (or 0 for tail rows) -------------
    #pragma unroll
    for (int ii = 0; ii < 12; ++ii) {
        const int rl = wv * 12 + ii;
        const int r  = row0 + rl;
        float2 v = (r < N_NODES) ? x2[(size_t)r * 64 + lane]
                                 : make_float2(0.f, 0.f);
        *(float2*)(As + rl * SR + 2 * lane) = v;
    }
    if (tid < TR) {
        int r = row0 + tid;
        batch_l[tid] = (r < N_NODES) ? batch[r] : (N_GRAPHS - 1);
    }
    __syncthreads();

    // ---- edge accumulate: wave wv handles its quarter of the bucket ------
    {
        const int n = min(((const int*)ws + WS_CUR)[tile], CAP);
        const int* __restrict__ gb = (const int*)ws + WS_BUCK + tile * CAP;
        const int per = (n + 3) >> 2;
        const int e0 = wv * per;
        const int e1 = min(e0 + per, n);
        for (int base = e0; base < e1; base += 64) {
            const int cnt = min(64, e1 - base);
            int pk = (base + lane < e1) ? gb[base + lane] : 0;
            int j = 0;
            for (; j + 4 <= cnt; j += 4) {
                int p0 = __shfl(pk, j),     p1 = __shfl(pk, j + 1);
                int p2 = __shfl(pk, j + 2), p3 = __shfl(pk, j + 3);
                __half2 v0 = xh2[(size_t)(p0 & 0xFFFF) * 64 + lane];
                __half2 v1 = xh2[(size_t)(p1 & 0xFFFF) * 64 + lane];
                __half2 v2 = xh2[(size_t)(p2 & 0xFFFF) * 64 + lane];
                __half2 v3 = xh2[(size_t)(p3 & 0xFFFF) * 64 + lane];
                float2 f0 = __half22float2(v0);
                float2 f1 = __half22float2(v1);
                float2 f2 = __half22float2(v2);
                float2 f3 = __half22float2(v3);
                atomicAdd(&As[(p0 >> 16) * SR + 2 * lane],     f0.x);
                atomicAdd(&As[(p0 >> 16) * SR + 2 * lane + 1], f0.y);
                atomicAdd(&As[(p1 >> 16) * SR + 2 * lane],     f1.x);
                atomicAdd(&As[(p1 >> 16) * SR + 2 * lane + 1], f1.y);
                atomicAdd(&As[(p2 >> 16) * SR + 2 * lane],     f2.x);
                atomicAdd(&As[(p2 >> 16) * SR + 2 * lane + 1], f2.y);
                atomicAdd(&As[(p3 >> 16) * SR + 2 * lane],     f3.x);
                atomicAdd(&As[(p3 >> 16) * SR + 2 * lane + 1], f3.y);
            }
            for (; j < cnt; ++j) {
                int p0 = __shfl(pk, j);
                float2 f0 = __half22float2(xh2[(size_t)(p0 & 0xFFFF) * 64 + lane]);
                atomicAdd(&As[(p0 >> 16) * SR + 2 * lane],     f0.x);
                atomicAdd(&As[(p0 >> 16) * SR + 2 * lane + 1], f0.y);
            }
        }
    }
    __syncthreads();

    // ---- layer 1: acc = relu(As @ W1a + b1a), kept in registers ----------
    float acc[3][8];
    #pragma unroll
    for (int i = 0; i < 3; ++i)
        #pragma unroll
        for (int j = 0; j < 8; ++j) acc[i][j] = 0.f;

    #pragma unroll 2
    for (int k = 0; k < N_FEAT; k += 4) {
        float4 w[8];
        #pragma unroll
        for (int kk = 0; kk < 4; ++kk) {
            w[2 * kk]     = *(const float4*)(W1a + (k + kk) * N_FEAT + fg * 8);
            w[2 * kk + 1] = *(const float4*)(W1a + (k + kk) * N_FEAT + fg * 8 + 4);
        }
        #pragma unroll
        for (int i = 0; i < 3; ++i) {
            const float4 a4 = *(const float4*)(As + (rg * 3 + i) * SR + k);
            const float av[4] = {a4.x, a4.y, a4.z, a4.w};
            #pragma unroll
            for (int kk = 0; kk < 4; ++kk) {
                acc[i][0] += av[kk] * w[2 * kk].x;
                acc[i][1] += av[kk] * w[2 * kk].y;
                acc[i][2] += av[kk] * w[2 * kk].z;
                acc[i][3] += av[kk] * w[2 * kk].w;
                acc[i][4] += av[kk] * w[2 * kk + 1].x;
                acc[i][5] += av[kk] * w[2 * kk + 1].y;
                acc[i][6] += av[kk] * w[2 * kk + 1].z;
                acc[i][7] += av[kk] * w[2 * kk + 1].w;
            }
        }
    }
    __syncthreads();   // everyone done reading As before overwrite

    {
        const float4 ba0 = *(const float4*)(b1a + fg * 8);
        const float4 ba1 = *(const float4*)(b1a + fg * 8 + 4);
        #pragma unroll
        for (int i = 0; i < 3; ++i) {
            float4 u0, u1;
            u0.x = fmaxf(acc[i][0] + ba0.x, 0.f); u0.y = fmaxf(acc[i][1] + ba0.y, 0.f);
            u0.z = fmaxf(acc[i][2] + ba0.z, 0.f); u0.w = fmaxf(acc[i][3] + ba0.w, 0.f);
            u1.x = fmaxf(acc[i][4] + ba1.x, 0.f); u1.y = fmaxf(acc[i][5] + ba1.y, 0.f);
            u1.z = fmaxf(acc[i][6] + ba1.z, 0.f); u1.w = fmaxf(acc[i][7] + ba1.w, 0.f);
            *(float4*)(As + (rg * 3 + i) * SR + fg * 8)     = u0;
            *(float4*)(As + (rg * 3 + i) * SR + fg * 8 + 4) = u1;
        }
    }
    __syncthreads();

    // ---- layer 2: x1 = relu(As @ W1b + b1b) -> back into As ---------------
    #pragma unroll
    for (int i = 0; i < 3; ++i)
        #pragma unroll
        for (int j = 0; j < 8; ++j) acc[i][j] = 0.f;

    #pragma unroll 2
    for (int k = 0; k < N_FEAT; k += 4) {
        float4 w[8];
        #pragma unroll
        for (int kk = 0; kk < 4; ++kk) {
            w[2 * kk]     = *(const float4*)(W1b + (k + kk) * N_FEAT + fg * 8);
            w[2 * kk + 1] = *(const float4*)(W1b + (k + kk) * N_FEAT + fg * 8 + 4);
        }
        #pragma unroll
        for (int i = 0; i < 3; ++i) {
            const float4 a4 = *(const float4*)(As + (rg * 3 + i) * SR + k);
            const float av[4] = {a4.x, a4.y, a4.z, a4.w};
            #pragma unroll
            for (int kk = 0; kk < 4; ++kk) {
                acc[i][0] += av[kk] * w[2 * kk].x;
                acc[i][1] += av[kk] * w[2 * kk].y;
                acc[i][2] += av[kk] * w[2 * kk].z;
                acc[i][3] += av[kk] * w[2 * kk].w;
                acc[i][4] += av[kk] * w[2 * kk + 1].x;
                acc[i][5] += av[kk] * w[2 * kk + 1].y;
                acc[i][6] += av[kk] * w[2 * kk + 1].z;
                acc[i][7] += av[kk] * w[2 * kk + 1].w;
            }
        }
    }
    __syncthreads();   // done reading layer-1 As before overwrite with x1

    {
        const float4 bb0 = *(const float4*)(b1b + fg * 8);
        const float4 bb1 = *(const float4*)(b1b + fg * 8 + 4);
        #pragma unroll
        for (int i = 0; i < 3; ++i) {
            float4 u0, u1;
            u0.x = fmaxf(acc[i][0] + bb0.x, 0.f); u0.y = fmaxf(acc[i][1] + bb0.y, 0.f);
            u0.z = fmaxf(acc[i][2] + bb0.z, 0.f); u0.w = fmaxf(acc[i][3] + bb0.w, 0.f);
            u1.x = fmaxf(acc[i][4] + bb1.x, 0.f); u1.y = fmaxf(acc[i][5] + bb1.y, 0.f);
            u1.z = fmaxf(acc[i][6] + bb1.z, 0.f); u1.w = fmaxf(acc[i][7] + bb1.w, 0.f);
            *(float4*)(As + (rg * 3 + i) * SR + fg * 8)     = u0;
            *(float4*)(As + (rg * 3 + i) * SR + fg * 8 + 4) = u1;
        }
    }
    __syncthreads();

    // ---- epilogue: BN-stat partials + raw pooled-sum partials -------------
    {
        const int c = tid & 127;
        const int h = tid >> 7;
        float sum = 0.f, sq = 0.f, pool = 0.f;
        int curg = batch_l[h * 24];
        bool any = (row0 + h * 24) < N_NODES;
        #pragma unroll 4
        for (int rr = 0; rr < 24; ++rr) {
            int rl = h * 24 + rr;
            if (row0 + rl >= N_NODES) break;
            float v = As[rl * SR + c];
            int g = batch_l[rl];
            if (g != curg) {   // wave-uniform branch (same rows across lanes)
                unsafeAtomicAdd(ws + WS_XG + (size_t)curg * N_FEAT + c, pool);
                pool = 0.f; curg = g;
            }
            sum += v; sq += v * v; pool += v;
        }
        if (any) unsafeAtomicAdd(ws + WS_XG + (size_t)curg * N_FEAT + c, pool);
        if (h == 1) { red[c] = sum; red[128 + c] = sq; }
        __syncthreads();
        if (h == 0) {
            unsafeAtomicAdd(ws + WS_STATS + c, sum + red[c]);
            unsafeAtomicAdd(ws + WS_STATS + 128 + c, sq + red[128 + c]);
        }
    }
}

__device__ __forceinline__ int lbound(const int* __restrict__ a, int n, int v) {
    int lo = 0, hi = n;
    while (lo < hi) { int m = (lo + hi) >> 1; if (a[m] < v) lo = m + 1; else hi = m; }
    return lo;
}

// --------- 10-iter gated recurrence + output MLP, block per graph -----------
__global__ __launch_bounds__(256) void k_recur(const float* __restrict__ ws,
        const int* __restrict__ batch,
        const float* __restrict__ gamma, const float* __restrict__ beta,
        const float* __restrict__ Wl1, const float* __restrict__ bl1,
        const float* __restrict__ Wl2, const float* __restrict__ bl2,
        const float* __restrict__ Wm1, const float* __restrict__ bm1,
        const float* __restrict__ Wm2, const float* __restrict__ bm2,
        float* __restrict__ out) {
    __shared__ float W1h[128 * 64];
    __shared__ float W2h[128 * 64];
    __shared__ float xg_s[128];
    __shared__ float h_s[128];
    __shared__ float px[2][64];
    __shared__ float pq[2][2][64];
    __shared__ float m_s[DIMM];
    __shared__ int range[2];
    const int g = blockIdx.x, tid = threadIdx.x;

    if (tid < 2) range[tid] = lbound(batch, N_NODES, g + tid);
    {   // vectorized weight staging: 8192 floats each = 2048 float4
        const float4* w1 = (const float4*)(Wl1 + 128 * 64);
        const float4* w2 = (const float4*)(Wl2 + 128 * 64);
        float4* d1 = (float4*)W1h;
        float4* d2 = (float4*)W2h;
        #pragma unroll
        for (int i = 0; i < 8; ++i) {
            d1[tid + i * 256] = w1[tid + i * 256];
            d2[tid + i * 256] = w2[tid + i * 256];
        }
    }
    __syncthreads();
    if (tid < 128) {
        const int cnt = range[1] - range[0];
        float mean = ws[WS_STATS + tid] * (1.f / N_NODES);
        float var  = fmaxf(ws[WS_STATS + 128 + tid] * (1.f / N_NODES) - mean * mean, 0.f);
        float sc = gamma[tid] * rsqrtf(var + 1e-5f);
        float sh = beta[tid] - mean * sc;
        float pool = ws[WS_XG + (size_t)g * N_FEAT + tid];
        float v = (cnt > 0) ? (sc * pool / (float)cnt + sh) : 0.f;
        xg_s[tid] = v;
        h_s[tid] = v;
    }
    __syncthreads();

    const int sel  = tid >> 7;
    const int part = (tid >> 6) & 1;
    const int j    = tid & 63;

    {
        const float* Wg = sel ? Wl2 : Wl1;
        float a = 0.f;
        const int k0 = part * 64;
        #pragma unroll 4
        for (int k = 0; k < 64; ++k) a += xg_s[k0 + k] * Wg[(k0 + k) * 64 + j];
        pq[sel][part][j] = a;
    }
    __syncthreads();
    if (part == 0) {
        const float* bias = sel ? bl2 : bl1;
        px[sel][j] = pq[sel][0][j] + pq[sel][1][j] + bias[j];
    }
    __syncthreads();

    const float* Wh = sel ? W2h : W1h;
    for (int it = 0; it < N_ITERS; ++it) {
        float a = 0.f;
        const int k0 = part * 64;
        #pragma unroll
        for (int k = 0; k < 64; k += 4) {
            const float4 h4 = *(const float4*)(h_s + k0 + k);
            a += h4.x * Wh[(k0 + k + 0) * 64 + j];
            a += h4.y * Wh[(k0 + k + 1) * 64 + j];
            a += h4.z * Wh[(k0 + k + 2) * 64 + j];
            a += h4.w * Wh[(k0 + k + 3) * 64 + j];
        }
        pq[sel][part][j] = a;
        __syncthreads();
        if (part == 0) {
            float tot = pq[sel][0][j] + pq[sel][1][j] + px[sel][j];
            if (sel == 0) h_s[64 + j] = 1.f / (1.f + expf(-tot));
            else          h_s[j] = tanhf(tot);
        }
        __syncthreads();
    }

    if (tid < DIMM) {
        float a = bm1[tid];
        #pragma unroll 4
        for (int k = 0; k < 128; ++k) a += h_s[k] * Wm1[k * DIMM + tid];
        m_s[tid] = fmaxf(a, 0.f);
    }
    __syncthreads();
    if (tid < N_OUTD) {
        float a = bm2[tid];
        for (int k = 0; k < DIMM; ++k) a += m_s[k] * Wm2[k * N_OUTD + tid];
        out[g * N_OUTD + tid] = a;
    }
}

extern "C" void kernel_launch(void* const* d_in, const int* in_sizes, int n_in,
                              void* d_out, int out_size, void* d_ws, size_t ws_size,
                              hipStream_t stream) {
    const float* x     = (const float*)d_in[0];
    const int*   ei    = (const int*)d_in[1];
    const int*   batch = (const int*)d_in[2];
    const float* W1a = (const float*)d_in[3];
    const float* b1a = (const float*)d_in[4];
    const float* W1b = (const float*)d_in[5];
    const float* b1b = (const float*)d_in[6];
    const float* gamma = (const float*)d_in[7];
    const float* beta  = (const float*)d_in[8];
    const float* Wl1 = (const float*)d_in[9];
    const float* bl1 = (const float*)d_in[10];
    const float* Wl2 = (const float*)d_in[11];
    const float* bl2 = (const float*)d_in[12];
    const float* Wm1 = (const float*)d_in[13];
    const float* bm1 = (const float*)d_in[14];
    const float* Wm2 = (const float*)d_in[15];
    const float* bm2 = (const float*)d_in[16];
    float* out = (float*)d_out;
    float* ws  = (float*)d_ws;

    k_pre   <<<512, 256, 0, stream>>>(x, ws);
    k_bucket<<<(N_EDGES + 255) / 256, 256, 0, stream>>>(ei, ws);
    k_fused <<<N_TILES, 256, 0, stream>>>(x, batch, ws, W1a, b1a, W1b, b1b);
    k_recur <<<N_GRAPHS, 256, 0, stream>>>(ws, batch, gamma, beta,
                                           Wl1, bl1, Wl2, bl2, Wm1, bm1, Wm2, bm2, out);
}

// Round 14
// 276.822 us; speedup vs baseline: 2.8009x; 2.8009x over previous
//
#include <hip/hip_runtime.h>
#include <hip/hip_fp16.h>
#include <cstddef>

#define N_NODES  50000
#define N_EDGES  600000
#define N_FEAT   128
#define N_GRAPHS 256
#define DIMM     95
#define N_OUTD   12
#define N_ITERS  10

#define SR 132   // padded LDS row stride (128+4); 132*4B = 16B-aligned rows
#define TR 48    // rows per block tile (-> 1042 blocks -> 4+ blocks/CU)
#define CAPR 40  // slots per node row (deg ~Poisson(12); P(>40) ~ 5e-6)

// workspace layout (float-element offsets; int/ushort/half arrays reinterpret)
// total 4,283,024 floats = 17.1 MB  (< 18.7 MB proven in use by R11)
#define WS_STATS 0                         // [256] colsum[128], colsumsq[128]
#define WS_XG    (WS_STATS + 256)          // [256*128] raw pooled sums
#define WS_CNT   (WS_XG + N_GRAPHS * N_FEAT)   // int[50000] per-node degree/cursor
#define WS_RB    (WS_CNT + N_NODES)            // ushort[50000*40] per-row src lists
#define WS_XH    (WS_RB + N_NODES * CAPR / 2)  // half[50000*128] fp16 x table

// ---- prep: zero stats/pools/counters + cast x->fp16 ------------------------
__global__ void k_pre(const float* __restrict__ x, float* __restrict__ ws) {
    const int gtid = blockIdx.x * 256 + threadIdx.x;
    const int nthr = gridDim.x * 256;
    for (int i = gtid; i < 256 + N_GRAPHS * N_FEAT; i += nthr) ws[i] = 0.f;
    int* cnt = (int*)ws + WS_CNT;
    for (int i = gtid; i < N_NODES; i += nthr) cnt[i] = 0;
    const float4* __restrict__ x4 = (const float4*)x;
    float2* __restrict__ xh = (float2*)(ws + WS_XH);
    for (int i = gtid; i < N_NODES * 32; i += nthr) {
        float4 v = x4[i];
        float2 o;
        ((__half2*)&o)[0] = __float22half2_rn(make_float2(v.x, v.y));
        ((__half2*)&o)[1] = __float22half2_rn(make_float2(v.z, v.w));
        xh[i] = o;
    }
}

// ---- per-ROW bucket scatter: ONE pass, replaces hist+scan+scatter ----------
// rb[d*CAPR + pos] = src. Row src-SET is deterministic (slot order is not;
// fp32 reorder jitter ~1e-6 at h0 -> ~4e-6 at output, negligible).
__global__ void k_bucket(const int* __restrict__ ei, float* __restrict__ ws) {
    int e = blockIdx.x * 256 + threadIdx.x;
    if (e >= N_EDGES) return;
    int d = ei[N_EDGES + e];
    int s = ei[e];
    int* cnt = (int*)ws + WS_CNT;
    int pos = atomicAdd(&cnt[d], 1);
    if (pos < CAPR) ((unsigned short*)(ws + WS_RB))[d * CAPR + pos] = (unsigned short)s;
}

// ---- fused: per-row gather (fp16 table) + 2-layer MLP + stats/pool partials
// Gather structure verbatim from R10 (split-wave dual-row, register acc);
// only the CSR addressing changed: lo = r*CAPR, deg = min(cnt[r], CAPR).
__global__ __launch_bounds__(256, 4) void k_fused(const float* __restrict__ x,
        const int* __restrict__ batch, float* __restrict__ ws,
        const float* __restrict__ W1a, const float* __restrict__ b1a,
        const float* __restrict__ W1b, const float* __restrict__ b1b) {
    __shared__ float As[TR * SR];
    __shared__ float red[256];
    __shared__ int batch_l[TR];
    const int tid  = threadIdx.x;
    const int lane = tid & 63;
    const int wv   = tid >> 6;
    const int half = lane >> 5;    // 0: row A of pair, 1: row B
    const int sl   = lane & 31;    // sub-lane: 4-col group
    const int fg   = tid & 15;     // 16 feat groups x 8 cols (MLP)
    const int rg   = tid >> 4;     // 16 row groups  x 3 rows (MLP)
    const int row0 = blockIdx.x * TR;

    const int* __restrict__ cnt = (const int*)ws + WS_CNT;
    const unsigned short* __restrict__ rb = (const unsigned short*)(ws + WS_RB);
    const float4* __restrict__ x4 = (const float4*)x;
    const float2* __restrict__ xh = (const float2*)(ws + WS_XH);  // 32 float2/row

    if (tid < TR) {
        int r = row0 + tid;
        batch_l[tid] = (r < N_NODES) ? batch[r] : (N_GRAPHS - 1);
    }

    // ---- gather: wave wv owns rows [wv*12, wv*12+12) as 6 pairs, 2 pairs
    // (4 rows) in flight; each j-step issues 4 independent dual-row loads.
    for (int ii = 0; ii < 12; ii += 4) {
        float4 acc[2];
        int lo[2], deg[2];
        int need = 0;
        #pragma unroll
        for (int p = 0; p < 2; ++p) {
            const int rl = wv * 12 + ii + 2 * p + half;
            const int r  = row0 + rl;
            const bool valid = r < N_NODES;
            lo[p]  = r * CAPR;
            deg[p] = valid ? min(cnt[r], CAPR) : 0;
            acc[p] = valid ? x4[(size_t)r * 32 + sl] : make_float4(0.f, 0.f, 0.f, 0.f);
            int dmx = max(deg[p], __shfl_xor(deg[p], 32));  // pair max (both halves)
            need = max(need, dmx);
        }
        for (int c0 = 0; c0 < need; c0 += 32) {
            int idxp[2];
            #pragma unroll
            for (int p = 0; p < 2; ++p)
                idxp[p] = (c0 + sl < deg[p]) ? (int)rb[lo[p] + c0 + sl] : 0;
            const int dmc = min(32, need - c0);
            for (int j = 0; j < dmc; j += 2) {
                float2 v[4];
                #pragma unroll
                for (int p = 0; p < 2; ++p) {
                    int s0 = __shfl(idxp[p], (half << 5) + j);
                    v[p] = (c0 + j < deg[p]) ? xh[(size_t)s0 * 32 + sl]
                                             : make_float2(0.f, 0.f);
                }
                #pragma unroll
                for (int p = 0; p < 2; ++p) {
                    int s1 = __shfl(idxp[p], (half << 5) + j + 1);
                    v[2 + p] = (c0 + j + 1 < deg[p]) ? xh[(size_t)s1 * 32 + sl]
                                                     : make_float2(0.f, 0.f);
                }
                #pragma unroll
                for (int p = 0; p < 2; ++p) {
                    float2 a01 = __half22float2(((const __half2*)&v[p])[0]);
                    float2 a23 = __half22float2(((const __half2*)&v[p])[1]);
                    float2 b01 = __half22float2(((const __half2*)&v[2 + p])[0]);
                    float2 b23 = __half22float2(((const __half2*)&v[2 + p])[1]);
                    acc[p].x += a01.x + b01.x;
                    acc[p].y += a01.y + b01.y;
                    acc[p].z += a23.x + b23.x;
                    acc[p].w += a23.y + b23.y;
                }
            }
        }
        #pragma unroll
        for (int p = 0; p < 2; ++p) {
            const int rl = wv * 12 + ii + 2 * p + half;
            *(float4*)(As + rl * SR + 4 * sl) = acc[p];
        }
    }
    __syncthreads();

    // ---- layer 1: acc = relu(As @ W1a + b1a), kept in registers ----------
    float acc[3][8];
    #pragma unroll
    for (int i = 0; i < 3; ++i)
        #pragma unroll
        for (int j = 0; j < 8; ++j) acc[i][j] = 0.f;

    #pragma unroll 2
    for (int k = 0; k < N_FEAT; k += 4) {
        float4 w[8];
        #pragma unroll
        for (int kk = 0; kk < 4; ++kk) {
            w[2 * kk]     = *(const float4*)(W1a + (k + kk) * N_FEAT + fg * 8);
            w[2 * kk + 1] = *(const float4*)(W1a + (k + kk) * N_FEAT + fg * 8 + 4);
        }
        #pragma unroll
        for (int i = 0; i < 3; ++i) {
            const float4 a4 = *(const float4*)(As + (rg * 3 + i) * SR + k);
            const float av[4] = {a4.x, a4.y, a4.z, a4.w};
            #pragma unroll
            for (int kk = 0; kk < 4; ++kk) {
                acc[i][0] += av[kk] * w[2 * kk].x;
                acc[i][1] += av[kk] * w[2 * kk].y;
                acc[i][2] += av[kk] * w[2 * kk].z;
                acc[i][3] += av[kk] * w[2 * kk].w;
                acc[i][4] += av[kk] * w[2 * kk + 1].x;
                acc[i][5] += av[kk] * w[2 * kk + 1].y;
                acc[i][6] += av[kk] * w[2 * kk + 1].z;
                acc[i][7] += av[kk] * w[2 * kk + 1].w;
            }
        }
    }
    __syncthreads();   // everyone done reading As before overwrite

    {
        const float4 ba0 = *(const float4*)(b1a + fg * 8);
        const float4 ba1 = *(const float4*)(b1a + fg * 8 + 4);
        #pragma unroll
        for (int i = 0; i < 3; ++i) {
            float4 u0, u1;
            u0.x = fmaxf(acc[i][0] + ba0.x, 0.f); u0.y = fmaxf(acc[i][1] + ba0.y, 0.f);
            u0.z = fmaxf(acc[i][2] + ba0.z, 0.f); u0.w = fmaxf(acc[i][3] + ba0.w, 0.f);
            u1.x = fmaxf(acc[i][4] + ba1.x, 0.f); u1.y = fmaxf(acc[i][5] + ba1.y, 0.f);
            u1.z = fmaxf(acc[i][6] + ba1.z, 0.f); u1.w = fmaxf(acc[i][7] + ba1.w, 0.f);
            *(float4*)(As + (rg * 3 + i) * SR + fg * 8)     = u0;
            *(float4*)(As + (rg * 3 + i) * SR + fg * 8 + 4) = u1;
        }
    }
    __syncthreads();

    // ---- layer 2: x1 = relu(As @ W1b + b1b) -> back into As ---------------
    #pragma unroll
    for (int i = 0; i < 3; ++i)
        #pragma unroll
        for (int j = 0; j < 8; ++j) acc[i][j] = 0.f;

    #pragma unroll 2
    for (int k = 0; k < N_FEAT; k += 4) {
        float4 w[8];
        #pragma unroll
        for (int kk = 0; kk < 4; ++kk) {
            w[2 * kk]     = *(const float4*)(W1b + (k + kk) * N_FEAT + fg * 8);
            w[2 * kk + 1] = *(const float4*)(W1b + (k + kk) * N_FEAT + fg * 8 + 4);
        }
        #pragma unroll
        for (int i = 0; i < 3; ++i) {
            const float4 a4 = *(const float4*)(As + (rg * 3 + i) * SR + k);
            const float av[4] = {a4.x, a4.y, a4.z, a4.w};
            #pragma unroll
            for (int kk = 0; kk < 4; ++kk) {
                acc[i][0] += av[kk] * w[2 * kk].x;
                acc[i][1] += av[kk] * w[2 * kk].y;
                acc[i][2] += av[kk] * w[2 * kk].z;
                acc[i][3] += av[kk] * w[2 * kk].w;
                acc[i][4] += av[kk] * w[2 * kk + 1].x;
                acc[i][5] += av[kk] * w[2 * kk + 1].y;
                acc[i][6] += av[kk] * w[2 * kk + 1].z;
                acc[i][7] += av[kk] * w[2 * kk + 1].w;
            }
        }
    }
    __syncthreads();   // done reading layer-1 As before overwrite with x1

    {
        const float4 bb0 = *(const float4*)(b1b + fg * 8);
        const float4 bb1 = *(const float4*)(b1b + fg * 8 + 4);
        #pragma unroll
        for (int i = 0; i < 3; ++i) {
            float4 u0, u1;
            u0.x = fmaxf(acc[i][0] + bb0.x, 0.f); u0.y = fmaxf(acc[i][1] + bb0.y, 0.f);
            u0.z = fmaxf(acc[i][2] + bb0.z, 0.f); u0.w = fmaxf(acc[i][3] + bb0.w, 0.f);
            u1.x = fmaxf(acc[i][4] + bb1.x, 0.f); u1.y = fmaxf(acc[i][5] + bb1.y, 0.f);
            u1.z = fmaxf(acc[i][6] + bb1.z, 0.f); u1.w = fmaxf(acc[i][7] + bb1.w, 0.f);
            *(float4*)(As + (rg * 3 + i) * SR + fg * 8)     = u0;
            *(float4*)(As + (rg * 3 + i) * SR + fg * 8 + 4) = u1;
        }
    }
    __syncthreads();

    // ---- epilogue: BN-stat partials + raw pooled-sum partials -------------
    {
        const int c = tid & 127;
        const int h = tid >> 7;
        float sum = 0.f, sq = 0.f, pool = 0.f;
        int curg = batch_l[h * 24];
        bool any = (row0 + h * 24) < N_NODES;
        #pragma unroll 4
        for (int rr = 0; rr < 24; ++rr) {
            int rl = h * 24 + rr;
            if (row0 + rl >= N_NODES) break;
            float v = As[rl * SR + c];
            int g = batch_l[rl];
            if (g != curg) {   // wave-uniform branch (same rows across lanes)
                unsafeAtomicAdd(ws + WS_XG + (size_t)curg * N_FEAT + c, pool);
                pool = 0.f; curg = g;
            }
            sum += v; sq += v * v; pool += v;
        }
        if (any) unsafeAtomicAdd(ws + WS_XG + (size_t)curg * N_FEAT + c, pool);
        if (h == 1) { red[c] = sum; red[128 + c] = sq; }
        __syncthreads();
        if (h == 0) {
            unsafeAtomicAdd(ws + WS_STATS + c, sum + red[c]);
            unsafeAtomicAdd(ws + WS_STATS + 128 + c, sq + red[128 + c]);
        }
    }
}

__device__ __forceinline__ int lbound(const int* __restrict__ a, int n, int v) {
    int lo = 0, hi = n;
    while (lo < hi) { int m = (lo + hi) >> 1; if (a[m] < v) lo = m + 1; else hi = m; }
    return lo;
}

// --------- 10-iter gated recurrence + output MLP, block per graph -----------
__global__ __launch_bounds__(256) void k_recur(const float* __restrict__ ws,
        const int* __restrict__ batch,
        const float* __restrict__ gamma, const float* __restrict__ beta,
        const float* __restrict__ Wl1, const float* __restrict__ bl1,
        const float* __restrict__ Wl2, const float* __restrict__ bl2,
        const float* __restrict__ Wm1, const float* __restrict__ bm1,
        const float* __restrict__ Wm2, const float* __restrict__ bm2,
        float* __restrict__ out) {
    __shared__ float W1h[128 * 64];
    __shared__ float W2h[128 * 64];
    __shared__ float xg_s[128];
    __shared__ float h_s[128];
    __shared__ float px[2][64];
    __shared__ float pq[2][2][64];
    __shared__ float m_s[DIMM];
    __shared__ int range[2];
    const int g = blockIdx.x, tid = threadIdx.x;

    if (tid < 2) range[tid] = lbound(batch, N_NODES, g + tid);
    {   // vectorized weight staging: 8192 floats each = 2048 float4
        const float4* w1 = (const float4*)(Wl1 + 128 * 64);
        const float4* w2 = (const float4*)(Wl2 + 128 * 64);
        float4* d1 = (float4*)W1h;
        float4* d2 = (float4*)W2h;
        #pragma unroll
        for (int i = 0; i < 8; ++i) {
            d1[tid + i * 256] = w1[tid + i * 256];
            d2[tid + i * 256] = w2[tid + i * 256];
        }
    }
    __syncthreads();
    if (tid < 128) {
        const int cnt = range[1] - range[0];
        float mean = ws[WS_STATS + tid] * (1.f / N_NODES);
        float var  = fmaxf(ws[WS_STATS + 128 + tid] * (1.f / N_NODES) - mean * mean, 0.f);
        float sc = gamma[tid] * rsqrtf(var + 1e-5f);
        float sh = beta[tid] - mean * sc;
        float pool = ws[WS_XG + (size_t)g * N_FEAT + tid];
        float v = (cnt > 0) ? (sc * pool / (float)cnt + sh) : 0.f;
        xg_s[tid] = v;
        h_s[tid] = v;
    }
    __syncthreads();

    const int sel  = tid >> 7;
    const int part = (tid >> 6) & 1;
    const int j    = tid & 63;

    {
        const float* Wg = sel ? Wl2 : Wl1;
        float a = 0.f;
        const int k0 = part * 64;
        #pragma unroll 4
        for (int k = 0; k < 64; ++k) a += xg_s[k0 + k] * Wg[(k0 + k) * 64 + j];
        pq[sel][part][j] = a;
    }
    __syncthreads();
    if (part == 0) {
        const float* bias = sel ? bl2 : bl1;
        px[sel][j] = pq[sel][0][j] + pq[sel][1][j] + bias[j];
    }
    __syncthreads();

    const float* Wh = sel ? W2h : W1h;
    for (int it = 0; it < N_ITERS; ++it) {
        float a = 0.f;
        const int k0 = part * 64;
        #pragma unroll
        for (int k = 0; k < 64; k += 4) {
            const float4 h4 = *(const float4*)(h_s + k0 + k);
            a += h4.x * Wh[(k0 + k + 0) * 64 + j];
            a += h4.y * Wh[(k0 + k + 1) * 64 + j];
            a += h4.z * Wh[(k0 + k + 2) * 64 + j];
            a += h4.w * Wh[(k0 + k + 3) * 64 + j];
        }
        pq[sel][part][j] = a;
        __syncthreads();
        if (part == 0) {
            float tot = pq[sel][0][j] + pq[sel][1][j] + px[sel][j];
            if (sel == 0) h_s[64 + j] = 1.f / (1.f + expf(-tot));
            else          h_s[j] = tanhf(tot);
        }
        __syncthreads();
    }

    if (tid < DIMM) {
        float a = bm1[tid];
        #pragma unroll 4
        for (int k = 0; k < 128; ++k) a += h_s[k] * Wm1[k * DIMM + tid];
        m_s[tid] = fmaxf(a, 0.f);
    }
    __syncthreads();
    if (tid < N_OUTD) {
        float a = bm2[tid];
        for (int k = 0; k < DIMM; ++k) a += m_s[k] * Wm2[k * N_OUTD + tid];
        out[g * N_OUTD + tid] = a;
    }
}

extern "C" void kernel_launch(void* const* d_in, const int* in_sizes, int n_in,
                              void* d_out, int out_size, void* d_ws, size_t ws_size,
                              hipStream_t stream) {
    const float* x     = (const float*)d_in[0];
    const int*   ei    = (const int*)d_in[1];
    const int*   batch = (const int*)d_in[2];
    const float* W1a = (const float*)d_in[3];
    const float* b1a = (const float*)d_in[4];
    const float* W1b = (const float*)d_in[5];
    const float* b1b = (const float*)d_in[6];
    const float* gamma = (const float*)d_in[7];
    const float* beta  = (const float*)d_in[8];
    const float* Wl1 = (const float*)d_in[9];
    const float* bl1 = (const float*)d_in[10];
    const float* Wl2 = (const float*)d_in[11];
    const float* bl2 = (const float*)d_in[12];
    const float* Wm1 = (const float*)d_in[13];
    const float* bm1 = (const float*)d_in[14];
    const float* Wm2 = (const float*)d_in[15];
    const float* bm2 = (const float*)d_in[16];
    float* out = (float*)d_out;
    float* ws  = (float*)d_ws;

    k_pre   <<<512, 256, 0, stream>>>(x, ws);
    k_bucket<<<(N_EDGES + 255) / 256, 256, 0, stream>>>(ei, ws);
    k_fused <<<(N_NODES + TR - 1) / TR, 256, 0, stream>>>(x, batch, ws, W1a, b1a, W1b, b1b);
    k_recur <<<N_GRAPHS, 256, 0, stream>>>(ws, batch, gamma, beta,
                                           Wl1, bl1, Wl2, bl2, Wm1, bm1, Wm2, bm2, out);
}

// Round 15
// 276.108 us; speedup vs baseline: 2.8081x; 1.0026x over previous
//
#include <hip/hip_runtime.h>
#include <hip/hip_fp16.h>
#include <cstddef>

#define N_NODES  50000
#define N_EDGES  600000
#define N_FEAT   128
#define N_GRAPHS 256
#define DIMM     95
#define N_OUTD   12
#define N_ITERS  10

#define SR 132   // padded LDS row stride (128+4); 132*4B = 16B-aligned rows
#define TR 48    // rows per block tile (-> 1042 blocks -> 4+ blocks/CU)
#define CAPR 40  // slots per node row (deg ~Poisson(12); P(>40) ~ 5e-6)

// workspace layout (float-element offsets; int/ushort/half arrays reinterpret)
#define WS_STATS 0                         // [256] colsum[128], colsumsq[128]
#define WS_XG    (WS_STATS + 256)          // [256*128] raw pooled sums
#define WS_CNT   (WS_XG + N_GRAPHS * N_FEAT)   // int[50000] per-node degree/cursor
#define WS_RB    (WS_CNT + N_NODES)            // ushort[50000*40] per-row src lists
#define WS_XH    (WS_RB + N_NODES * CAPR / 2)  // half[50000*128] fp16 x table

// bytes to zero: stats(256f) + XG(32768f) + cnt(50000 int) — contiguous
#define WS_ZERO_BYTES ((256 + N_GRAPHS * N_FEAT + N_NODES) * 4)

// ---- prep: fp16 cast of x (BW-bound) + per-row bucket scatter (latency-bound)
// Both loops in one kernel so the atomic latency hides under the cast stream.
// cnt/stats/XG zeroed beforehand by hipMemsetAsync.
__global__ void k_prep(const int* __restrict__ ei, const float* __restrict__ x,
                       float* __restrict__ ws) {
    const int gtid = blockIdx.x * 256 + threadIdx.x;
    const int nthr = gridDim.x * 256;
    // loop A: cast x -> fp16 table (50000*32 float4 -> float2)
    const float4* __restrict__ x4 = (const float4*)x;
    float2* __restrict__ xh = (float2*)(ws + WS_XH);
    for (int i = gtid; i < N_NODES * 32; i += nthr) {
        float4 v = x4[i];
        float2 o;
        ((__half2*)&o)[0] = __float22half2_rn(make_float2(v.x, v.y));
        ((__half2*)&o)[1] = __float22half2_rn(make_float2(v.z, v.w));
        xh[i] = o;
    }
    // loop B: bucket scatter rb[d*CAPR + pos] = src
    if (gtid < N_EDGES) {
        int d = ei[N_EDGES + gtid];
        int s = ei[gtid];
        int* cnt = (int*)ws + WS_CNT;
        int pos = atomicAdd(&cnt[d], 1);
        if (pos < CAPR)
            ((unsigned short*)(ws + WS_RB))[d * CAPR + pos] = (unsigned short)s;
    }
}

// ---- fused: per-row gather (fp16 table) + 2-layer MLP + stats/pool partials
// Gather structure frozen from R10/R14 (split-wave dual-row, register acc).
__global__ __launch_bounds__(256, 4) void k_fused(const float* __restrict__ x,
        const int* __restrict__ batch, float* __restrict__ ws,
        const float* __restrict__ W1a, const float* __restrict__ b1a,
        const float* __restrict__ W1b, const float* __restrict__ b1b) {
    __shared__ float As[TR * SR];
    __shared__ float red[256];
    __shared__ int batch_l[TR];
    const int tid  = threadIdx.x;
    const int lane = tid & 63;
    const int wv   = tid >> 6;
    const int half = lane >> 5;    // 0: row A of pair, 1: row B
    const int sl   = lane & 31;    // sub-lane: 4-col group
    const int fg   = tid & 15;     // 16 feat groups x 8 cols (MLP)
    const int rg   = tid >> 4;     // 16 row groups  x 3 rows (MLP)
    const int row0 = blockIdx.x * TR;

    const int* __restrict__ cnt = (const int*)ws + WS_CNT;
    const unsigned short* __restrict__ rb = (const unsigned short*)(ws + WS_RB);
    const float4* __restrict__ x4 = (const float4*)x;
    const float2* __restrict__ xh = (const float2*)(ws + WS_XH);  // 32 float2/row

    if (tid < TR) {
        int r = row0 + tid;
        batch_l[tid] = (r < N_NODES) ? batch[r] : (N_GRAPHS - 1);
    }

    // ---- gather: wave wv owns rows [wv*12, wv*12+12) as 6 pairs, 2 pairs
    // (4 rows) in flight; each j-step issues 4 independent dual-row loads.
    for (int ii = 0; ii < 12; ii += 4) {
        float4 acc[2];
        int lo[2], deg[2];
        int need = 0;
        #pragma unroll
        for (int p = 0; p < 2; ++p) {
            const int rl = wv * 12 + ii + 2 * p + half;
            const int r  = row0 + rl;
            const bool valid = r < N_NODES;
            lo[p]  = r * CAPR;
            deg[p] = valid ? min(cnt[r], CAPR) : 0;
            acc[p] = valid ? x4[(size_t)r * 32 + sl] : make_float4(0.f, 0.f, 0.f, 0.f);
            int dmx = max(deg[p], __shfl_xor(deg[p], 32));  // pair max (both halves)
            need = max(need, dmx);
        }
        for (int c0 = 0; c0 < need; c0 += 32) {
            int idxp[2];
            #pragma unroll
            for (int p = 0; p < 2; ++p)
                idxp[p] = (c0 + sl < deg[p]) ? (int)rb[lo[p] + c0 + sl] : 0;
            const int dmc = min(32, need - c0);
            for (int j = 0; j < dmc; j += 2) {
                float2 v[4];
                #pragma unroll
                for (int p = 0; p < 2; ++p) {
                    int s0 = __shfl(idxp[p], (half << 5) + j);
                    v[p] = (c0 + j < deg[p]) ? xh[(size_t)s0 * 32 + sl]
                                             : make_float2(0.f, 0.f);
                }
                #pragma unroll
                for (int p = 0; p < 2; ++p) {
                    int s1 = __shfl(idxp[p], (half << 5) + j + 1);
                    v[2 + p] = (c0 + j + 1 < deg[p]) ? xh[(size_t)s1 * 32 + sl]
                                                     : make_float2(0.f, 0.f);
                }
                #pragma unroll
                for (int p = 0; p < 2; ++p) {
                    float2 a01 = __half22float2(((const __half2*)&v[p])[0]);
                    float2 a23 = __half22float2(((const __half2*)&v[p])[1]);
                    float2 b01 = __half22float2(((const __half2*)&v[2 + p])[0]);
                    float2 b23 = __half22float2(((const __half2*)&v[2 + p])[1]);
                    acc[p].x += a01.x + b01.x;
                    acc[p].y += a01.y + b01.y;
                    acc[p].z += a23.x + b23.x;
                    acc[p].w += a23.y + b23.y;
                }
            }
        }
        #pragma unroll
        for (int p = 0; p < 2; ++p) {
            const int rl = wv * 12 + ii + 2 * p + half;
            *(float4*)(As + rl * SR + 4 * sl) = acc[p];
        }
    }
    __syncthreads();

    // ---- layer 1: acc = relu(As @ W1a + b1a), kept in registers ----------
    float acc[3][8];
    #pragma unroll
    for (int i = 0; i < 3; ++i)
        #pragma unroll
        for (int j = 0; j < 8; ++j) acc[i][j] = 0.f;

    #pragma unroll 2
    for (int k = 0; k < N_FEAT; k += 4) {
        float4 w[8];
        #pragma unroll
        for (int kk = 0; kk < 4; ++kk) {
            w[2 * kk]     = *(const float4*)(W1a + (k + kk) * N_FEAT + fg * 8);
            w[2 * kk + 1] = *(const float4*)(W1a + (k + kk) * N_FEAT + fg * 8 + 4);
        }
        #pragma unroll
        for (int i = 0; i < 3; ++i) {
            const float4 a4 = *(const float4*)(As + (rg * 3 + i) * SR + k);
            const float av[4] = {a4.x, a4.y, a4.z, a4.w};
            #pragma unroll
            for (int kk = 0; kk < 4; ++kk) {
                acc[i][0] += av[kk] * w[2 * kk].x;
                acc[i][1] += av[kk] * w[2 * kk].y;
                acc[i][2] += av[kk] * w[2 * kk].z;
                acc[i][3] += av[kk] * w[2 * kk].w;
                acc[i][4] += av[kk] * w[2 * kk + 1].x;
                acc[i][5] += av[kk] * w[2 * kk + 1].y;
                acc[i][6] += av[kk] * w[2 * kk + 1].z;
                acc[i][7] += av[kk] * w[2 * kk + 1].w;
            }
        }
    }
    __syncthreads();   // everyone done reading As before overwrite

    {
        const float4 ba0 = *(const float4*)(b1a + fg * 8);
        const float4 ba1 = *(const float4*)(b1a + fg * 8 + 4);
        #pragma unroll
        for (int i = 0; i < 3; ++i) {
            float4 u0, u1;
            u0.x = fmaxf(acc[i][0] + ba0.x, 0.f); u0.y = fmaxf(acc[i][1] + ba0.y, 0.f);
            u0.z = fmaxf(acc[i][2] + ba0.z, 0.f); u0.w = fmaxf(acc[i][3] + ba0.w, 0.f);
            u1.x = fmaxf(acc[i][4] + ba1.x, 0.f); u1.y = fmaxf(acc[i][5] + ba1.y, 0.f);
            u1.z = fmaxf(acc[i][6] + ba1.z, 0.f); u1.w = fmaxf(acc[i][7] + ba1.w, 0.f);
            *(float4*)(As + (rg * 3 + i) * SR + fg * 8)     = u0;
            *(float4*)(As + (rg * 3 + i) * SR + fg * 8 + 4) = u1;
        }
    }
    __syncthreads();

    // ---- layer 2: x1 = relu(As @ W1b + b1b) -> back into As ---------------
    #pragma unroll
    for (int i = 0; i < 3; ++i)
        #pragma unroll
        for (int j = 0; j < 8; ++j) acc[i][j] = 0.f;

    #pragma unroll 2
    for (int k = 0; k < N_FEAT; k += 4) {
        float4 w[8];
        #pragma unroll
        for (int kk = 0; kk < 4; ++kk) {
            w[2 * kk]     = *(const float4*)(W1b + (k + kk) * N_FEAT + fg * 8);
            w[2 * kk + 1] = *(const float4*)(W1b + (k + kk) * N_FEAT + fg * 8 + 4);
        }
        #pragma unroll
        for (int i = 0; i < 3; ++i) {
            const float4 a4 = *(const float4*)(As + (rg * 3 + i) * SR + k);
            const float av[4] = {a4.x, a4.y, a4.z, a4.w};
            #pragma unroll
            for (int kk = 0; kk < 4; ++kk) {
                acc[i][0] += av[kk] * w[2 * kk].x;
                acc[i][1] += av[kk] * w[2 * kk].y;
                acc[i][2] += av[kk] * w[2 * kk].z;
                acc[i][3] += av[kk] * w[2 * kk].w;
                acc[i][4] += av[kk] * w[2 * kk + 1].x;
                acc[i][5] += av[kk] * w[2 * kk + 1].y;
                acc[i][6] += av[kk] * w[2 * kk + 1].z;
                acc[i][7] += av[kk] * w[2 * kk + 1].w;
            }
        }
    }
    __syncthreads();   // done reading layer-1 As before overwrite with x1

    {
        const float4 bb0 = *(const float4*)(b1b + fg * 8);
        const float4 bb1 = *(const float4*)(b1b + fg * 8 + 4);
        #pragma unroll
        for (int i = 0; i < 3; ++i) {
            float4 u0, u1;
            u0.x = fmaxf(acc[i][0] + bb0.x, 0.f); u0.y = fmaxf(acc[i][1] + bb0.y, 0.f);
            u0.z = fmaxf(acc[i][2] + bb0.z, 0.f); u0.w = fmaxf(acc[i][3] + bb0.w, 0.f);
            u1.x = fmaxf(acc[i][4] + bb1.x, 0.f); u1.y = fmaxf(acc[i][5] + bb1.y, 0.f);
            u1.z = fmaxf(acc[i][6] + bb1.z, 0.f); u1.w = fmaxf(acc[i][7] + bb1.w, 0.f);
            *(float4*)(As + (rg * 3 + i) * SR + fg * 8)     = u0;
            *(float4*)(As + (rg * 3 + i) * SR + fg * 8 + 4) = u1;
        }
    }
    __syncthreads();

    // ---- epilogue: BN-stat partials + raw pooled-sum partials -------------
    {
        const int c = tid & 127;
        const int h = tid >> 7;
        float sum = 0.f, sq = 0.f, pool = 0.f;
        int curg = batch_l[h * 24];
        bool any = (row0 + h * 24) < N_NODES;
        #pragma unroll 4
        for (int rr = 0; rr < 24; ++rr) {
            int rl = h * 24 + rr;
            if (row0 + rl >= N_NODES) break;
            float v = As[rl * SR + c];
            int g = batch_l[rl];
            if (g != curg) {   // wave-uniform branch (same rows across lanes)
                unsafeAtomicAdd(ws + WS_XG + (size_t)curg * N_FEAT + c, pool);
                pool = 0.f; curg = g;
            }
            sum += v; sq += v * v; pool += v;
        }
        if (any) unsafeAtomicAdd(ws + WS_XG + (size_t)curg * N_FEAT + c, pool);
        if (h == 1) { red[c] = sum; red[128 + c] = sq; }
        __syncthreads();
        if (h == 0) {
            unsafeAtomicAdd(ws + WS_STATS + c, sum + red[c]);
            unsafeAtomicAdd(ws + WS_STATS + 128 + c, sq + red[128 + c]);
        }
    }
}

__device__ __forceinline__ int lbound(const int* __restrict__ a, int n, int v) {
    int lo = 0, hi = n;
    while (lo < hi) { int m = (lo + hi) >> 1; if (a[m] < v) lo = m + 1; else hi = m; }
    return lo;
}

// --------- 10-iter gated recurrence + output MLP, block per graph -----------
__global__ __launch_bounds__(256) void k_recur(const float* __restrict__ ws,
        const int* __restrict__ batch,
        const float* __restrict__ gamma, const float* __restrict__ beta,
        const float* __restrict__ Wl1, const float* __restrict__ bl1,
        const float* __restrict__ Wl2, const float* __restrict__ bl2,
        const float* __restrict__ Wm1, const float* __restrict__ bm1,
        const float* __restrict__ Wm2, const float* __restrict__ bm2,
        float* __restrict__ out) {
    __shared__ float W1h[128 * 64];
    __shared__ float W2h[128 * 64];
    __shared__ float xg_s[128];
    __shared__ float h_s[128];
    __shared__ float px[2][64];
    __shared__ float pq[2][2][64];
    __shared__ float m_s[DIMM];
    __shared__ int range[2];
    const int g = blockIdx.x, tid = threadIdx.x;

    if (tid < 2) range[tid] = lbound(batch, N_NODES, g + tid);
    {   // vectorized weight staging: 8192 floats each = 2048 float4
        const float4* w1 = (const float4*)(Wl1 + 128 * 64);
        const float4* w2 = (const float4*)(Wl2 + 128 * 64);
        float4* d1 = (float4*)W1h;
        float4* d2 = (float4*)W2h;
        #pragma unroll
        for (int i = 0; i < 8; ++i) {
            d1[tid + i * 256] = w1[tid + i * 256];
            d2[tid + i * 256] = w2[tid + i * 256];
        }
    }
    __syncthreads();
    if (tid < 128) {
        const int cnt = range[1] - range[0];
        float mean = ws[WS_STATS + tid] * (1.f / N_NODES);
        float var  = fmaxf(ws[WS_STATS + 128 + tid] * (1.f / N_NODES) - mean * mean, 0.f);
        float sc = gamma[tid] * rsqrtf(var + 1e-5f);
        float sh = beta[tid] - mean * sc;
        float pool = ws[WS_XG + (size_t)g * N_FEAT + tid];
        float v = (cnt > 0) ? (sc * pool / (float)cnt + sh) : 0.f;
        xg_s[tid] = v;
        h_s[tid] = v;
    }
    __syncthreads();

    const int sel  = tid >> 7;
    const int part = (tid >> 6) & 1;
    const int j    = tid & 63;

    {
        const float* Wg = sel ? Wl2 : Wl1;
        float a = 0.f;
        const int k0 = part * 64;
        #pragma unroll 4
        for (int k = 0; k < 64; ++k) a += xg_s[k0 + k] * Wg[(k0 + k) * 64 + j];
        pq[sel][part][j] = a;
    }
    __syncthreads();
    if (part == 0) {
        const float* bias = sel ? bl2 : bl1;
        px[sel][j] = pq[sel][0][j] + pq[sel][1][j] + bias[j];
    }
    __syncthreads();

    const float* Wh = sel ? W2h : W1h;
    for (int it = 0; it < N_ITERS; ++it) {
        float a = 0.f;
        const int k0 = part * 64;
        #pragma unroll
        for (int k = 0; k < 64; k += 4) {
            const float4 h4 = *(const float4*)(h_s + k0 + k);
            a += h4.x * Wh[(k0 + k + 0) * 64 + j];
            a += h4.y * Wh[(k0 + k + 1) * 64 + j];
            a += h4.z * Wh[(k0 + k + 2) * 64 + j];
            a += h4.w * Wh[(k0 + k + 3) * 64 + j];
        }
        pq[sel][part][j] = a;
        __syncthreads();
        if (part == 0) {
            float tot = pq[sel][0][j] + pq[sel][1][j] + px[sel][j];
            if (sel == 0) h_s[64 + j] = 1.f / (1.f + expf(-tot));
            else          h_s[j] = tanhf(tot);
        }
        __syncthreads();
    }

    if (tid < DIMM) {
        float a = bm1[tid];
        #pragma unroll 4
        for (int k = 0; k < 128; ++k) a += h_s[k] * Wm1[k * DIMM + tid];
        m_s[tid] = fmaxf(a, 0.f);
    }
    __syncthreads();
    if (tid < N_OUTD) {
        float a = bm2[tid];
        for (int k = 0; k < DIMM; ++k) a += m_s[k] * Wm2[k * N_OUTD + tid];
        out[g * N_OUTD + tid] = a;
    }
}

extern "C" void kernel_launch(void* const* d_in, const int* in_sizes, int n_in,
                              void* d_out, int out_size, void* d_ws, size_t ws_size,
                              hipStream_t stream) {
    const float* x     = (const float*)d_in[0];
    const int*   ei    = (const int*)d_in[1];
    const int*   batch = (const int*)d_in[2];
    const float* W1a = (const float*)d_in[3];
    const float* b1a = (const float*)d_in[4];
    const float* W1b = (const float*)d_in[5];
    const float* b1b = (const float*)d_in[6];
    const float* gamma = (const float*)d_in[7];
    const float* beta  = (const float*)d_in[8];
    const float* Wl1 = (const float*)d_in[9];
    const float* bl1 = (const float*)d_in[10];
    const float* Wl2 = (const float*)d_in[11];
    const float* bl2 = (const float*)d_in[12];
    const float* Wm1 = (const float*)d_in[13];
    const float* bm1 = (const float*)d_in[14];
    const float* Wm2 = (const float*)d_in[15];
    const float* bm2 = (const float*)d_in[16];
    float* out = (float*)d_out;
    float* ws  = (float*)d_ws;

    hipMemsetAsync(ws, 0, WS_ZERO_BYTES, stream);
    k_prep <<<(N_EDGES + 255) / 256, 256, 0, stream>>>(ei, x, ws);
    k_fused<<<(N_NODES + TR - 1) / TR, 256, 0, stream>>>(x, batch, ws, W1a, b1a, W1b, b1b);
    k_recur<<<N_GRAPHS, 256, 0, stream>>>(ws, batch, gamma, beta,
                                          Wl1, bl1, Wl2, bl2, Wm1, bm1, Wm2, bm2, out);
}